// Round 11
// baseline (3279.140 us; speedup 1.0000x reference)
//
#include <hip/hip_runtime.h>
#include <hip/hip_bf16.h>
#include <hip/hip_cooperative_groups.h>

namespace cg = cooperative_groups;

#define B_ 32
#define S_ 512
#define IN_ 19
#define DE_ 256
#define DD_ 128
#define HE_ 8
#define HD_ 4
#define LE_ 6
#define LD_ 2
#define FE_ 1024
#define FD_ 512
#define DH_ 32
#define BS_ (B_ * S_)

typedef __attribute__((ext_vector_type(8))) short short8;
typedef __attribute__((ext_vector_type(4))) float f32x4;

__device__ __forceinline__ short f2bf(float f) {
    union { float f; unsigned u; } x; x.f = f;
    unsigned r = x.u + 0x7fff + ((x.u >> 16) & 1);
    return (short)(r >> 16);
}
__device__ __forceinline__ float bf2f(short s) {
    union { unsigned u; float f; } x; x.u = ((unsigned)(unsigned short)s) << 16;
    return x.f;
}

#define GLL16(g, l) __builtin_amdgcn_global_load_lds( \
    (const __attribute__((address_space(1))) void*)(g), \
    (__attribute__((address_space(3))) void*)(l), 16, 0, 0)

// (1/sqrt(32)) * log2(e), folded into Q at the QKV epilogue
#define QSCALE 0.2550653169f

// weight conversion table sizes
#define L_EQKV (LE_ * 3 * DE_ * DE_)
#define L_EOUT (LE_ * DE_ * DE_)
#define L_EF1  (LE_ * FE_ * DE_)
#define L_EF2  (LE_ * DE_ * FE_)
#define L_E2D  (DD_ * DE_)
#define L_DQKV (LD_ * 3 * DD_ * DD_)
#define L_DOUT (LD_ * DD_ * DD_)
#define L_DF1  (LD_ * FD_ * DD_)
#define L_DF2  (LD_ * DD_ * FD_)
#define CONV_TOTAL (L_EQKV + L_EOUT + L_EF1 + L_EF2 + L_E2D + L_DQKV + L_DOUT + L_DF1 + L_DF2)

struct MegaArgs {
    // raw inputs
    const float* ev; const int* am; const int* pm;
    const float* w_in; const float* b_in;
    const float* eqkv_b; const float* eout_b; const float* ef1_b; const float* ef2_b;
    const float* eg1; const float* eb1; const float* eg2; const float* eb2;
    const float* mask_tok;
    const float* dqkv_b; const float* dout_b; const float* df1_b; const float* df2_b;
    const float* dg1; const float* db1; const float* dg2; const float* db2;
    const float* qh_w; const float* qh_b; const float* dth_w; const float* dth_b;
    // fp32 weight sources (conv)
    const float* csrc[9];
    short* cdst[9];
    int clen[9];
    // ws
    int* counts; int* lengths; int* order; int* visible; int* idx;
    short* w_eqkv; short* w_eout; short* w_ef1; short* w_ef2; short* w_e2d;
    short* w_dqkv; short* w_dout; short* w_df1; short* w_df2;
    short* bx; short* qbuf; short* kbuf; short* vtbuf; short* battn; short* bt; short* hid;
    float* out;
};

// ---------------------------------------------------------------------------
// stage: weight fp32->bf16 (blocks >= 32)
// ---------------------------------------------------------------------------
__device__ __forceinline__ void conv_stage(const MegaArgs& a) {
    int base = (int)blockIdx.x - B_;
    int nth = ((int)gridDim.x - B_) * 256;
    for (int i = base * 256 + (int)threadIdx.x; i < CONV_TOTAL; i += nth) {
        int j = i;
#pragma unroll
        for (int e = 0; e < 9; ++e) {
            if (j < a.clen[e]) { a.cdst[e][j] = f2bf(a.csrc[e][j]); break; }
            j -= a.clen[e];
        }
    }
}

// ---------------------------------------------------------------------------
// stage: plan (blocks < 32), 256 threads handle 512 slots
// ---------------------------------------------------------------------------
__device__ __forceinline__ void plan_stage(char* smem, const MegaArgs& a) {
    int b = blockIdx.x;
    int* sc = (int*)smem;
    int s0 = threadIdx.x, s1 = threadIdx.x + 256;
    int a0 = (a.am[b * S_ + s0] != 0), v0 = a0 && (a.pm[b * S_ + s0] == 0);
    int a1 = (a.am[b * S_ + s1] != 0), v1 = a1 && (a.pm[b * S_ + s1] == 0);
    a.visible[b * S_ + s0] = v0;
    a.visible[b * S_ + s1] = v1;
    sc[s0] = v0 | (a0 << 16);
    sc[s1] = v1 | (a1 << 16);
    __syncthreads();
    for (int off = 1; off < S_; off <<= 1) {
        int t0 = (s0 >= off) ? sc[s0 - off] : 0;
        int t1 = (s1 >= off) ? sc[s1 - off] : 0;
        __syncthreads();
        sc[s0] += t0;
        sc[s1] += t1;
        __syncthreads();
    }
    int tot = sc[S_ - 1];
    int total = tot & 0xffff;
    if (threadIdx.x == 0) { a.counts[b] = total; a.lengths[b] = tot >> 16; }
    int incl0 = sc[s0] & 0xffff, incl1 = sc[s1] & 0xffff;
    a.idx[b * S_ + s0] = (incl0 > 0) ? incl0 - 1 : 0;
    a.idx[b * S_ + s1] = (incl1 > 0) ? incl1 - 1 : 0;
    if (v0) a.order[b * S_ + incl0 - 1] = s0; else a.order[b * S_ + total + (s0 - incl0)] = s0;
    if (v1) a.order[b * S_ + incl1 - 1] = s1; else a.order[b * S_ + total + (s1 - incl1)] = s1;
}

// ---------------------------------------------------------------------------
// stage: encoder embed — one wave per row
// ---------------------------------------------------------------------------
__device__ __forceinline__ void embed_stage(const MegaArgs& a) {
    int gw = blockIdx.x * 4 + (threadIdx.x >> 6), lane = threadIdx.x & 63;
    int nw = gridDim.x * 4;
    for (int bs = gw; bs < BS_; bs += nw) {
        int b = bs >> 9, s = bs & (S_ - 1);
        if (s >= a.counts[b]) {
#pragma unroll
            for (int j = 0; j < 4; ++j) a.bx[(size_t)bs * DE_ + j * 64 + lane] = 0;
            continue;
        }
        int src = a.order[bs];
        const float* e = a.ev + (size_t)(b * S_ + src) * IN_;
        float ebuf[IN_];
#pragma unroll
        for (int i = 0; i < IN_; ++i) ebuf[i] = e[i];
#pragma unroll
        for (int j = 0; j < 4; ++j) {
            int d = j * 64 + lane;
            float acc = a.b_in[d];
#pragma unroll
            for (int i = 0; i < IN_; ++i) acc += ebuf[i] * a.w_in[d * IN_ + i];
            a.bx[(size_t)bs * DE_ + d] = f2bf(acc);
        }
    }
}

// ---------------------------------------------------------------------------
// stage: LDS-staged MFMA GEMM (round-8 body), grid-stride over 128x128 tiles
// ---------------------------------------------------------------------------
template <bool RELU, bool QKV>
__device__ __forceinline__ void gemm_stage(char* smem,
    const short* A, const short* Wt, const float* bias,
    short* C, int M, int N, int K,
    short* qb, short* kb, short* vtb, int H, int D, const int* live) {
    short (*As)[32] = (short(*)[32])smem;
    short (*Bs)[32] = (short(*)[32])(smem + 8192);
    int t = threadIdx.x;
    int wave = t >> 6, lane = t & 63;
    int wm = (wave >> 1) * 64, wn = (wave & 1) * 64;
    int c = lane & 15, quad = lane >> 4;
    int nx = N >> 7;
    int ntiles = nx * (M >> 7);
    for (int tile = blockIdx.x; tile < ntiles; tile += gridDim.x) {
        int bm = (tile / nx) << 7, bn = (tile % nx) << 7;
        if (live && (bm & (S_ - 1)) >= live[bm >> 9]) continue;
        f32x4 acc[4][4];
#pragma unroll
        for (int i = 0; i < 4; ++i)
#pragma unroll
            for (int j = 0; j < 4; ++j) acc[i][j] = (f32x4){0.f, 0.f, 0.f, 0.f};
        const short* gA = A + (size_t)(bm + wave * 32 + (lane >> 2)) * K + (lane & 3) * 8;
        const short* gB = Wt + (size_t)(bn + wave * 32 + (lane >> 2)) * K + (lane & 3) * 8;
        for (int k0 = 0; k0 < K; k0 += 32) {
            GLL16(gA + k0, &As[wave * 32][0]);
            GLL16(gA + 16 * K + k0, &As[wave * 32 + 16][0]);
            GLL16(gB + k0, &Bs[wave * 32][0]);
            GLL16(gB + 16 * K + k0, &Bs[wave * 32 + 16][0]);
            __syncthreads();
            short8 af[4], bf[4];
#pragma unroll
            for (int i = 0; i < 4; ++i) af[i] = *(const short8*)&As[wm + i * 16 + c][quad * 8];
#pragma unroll
            for (int j = 0; j < 4; ++j) bf[j] = *(const short8*)&Bs[wn + j * 16 + c][quad * 8];
#pragma unroll
            for (int i = 0; i < 4; ++i)
#pragma unroll
                for (int j = 0; j < 4; ++j)
                    acc[i][j] = __builtin_amdgcn_mfma_f32_16x16x32_bf16(af[i], bf[j], acc[i][j], 0, 0, 0);
            __syncthreads();
        }
#pragma unroll
        for (int mt = 0; mt < 4; ++mt)
#pragma unroll
            for (int nt = 0; nt < 4; ++nt)
#pragma unroll
                for (int r = 0; r < 4; ++r) {
                    int R = bm + wm + mt * 16 + quad * 4 + r;
                    int Ncol = bn + wn + nt * 16 + c;
                    float v = acc[mt][nt][r] + (bias ? bias[Ncol] : 0.f);
                    if (RELU) v = fmaxf(v, 0.f);
                    if (!QKV) {
                        C[(size_t)R * N + Ncol] = f2bf(v);
                    } else {
                        int s = R & (S_ - 1), b2 = R >> 9;
                        if (Ncol < D) {
                            int h = Ncol >> 5, d = Ncol & 31;
                            qb[(((size_t)b2 * H + h) * S_ + s) * DH_ + d] = f2bf(v * QSCALE);
                        } else if (Ncol < 2 * D) {
                            int n2 = Ncol - D, h = n2 >> 5, d = n2 & 31;
                            kb[(((size_t)b2 * H + h) * S_ + s) * DH_ + d] = f2bf(v);
                        } else {
                            int n2 = Ncol - 2 * D, h = n2 >> 5, d = n2 & 31;
                            vtb[(((size_t)b2 * H + h) * DH_ + d) * S_ + s] = f2bf(v);
                        }
                    }
                }
    }
}

// ---------------------------------------------------------------------------
// stage: flash attention, grid-stride over (qtile64, h, b) items
// ---------------------------------------------------------------------------
__device__ __forceinline__ void attn_stage(char* smem,
    const short* qb, const short* kb, const short* vtb,
    const int* limit_arr, const int* qlim, short* o, int H, int D) {
    int wave = threadIdx.x >> 6, lane = threadIdx.x & 63;
    int c = lane & 15, quad = lane >> 4;
    short (*Pt)[132] = (short(*)[132])(smem + wave * 16 * 132 * 2);
    f32x4 zero = (f32x4){0.f, 0.f, 0.f, 0.f};
    int nitems = 8 * H * B_;
    for (int item = blockIdx.x; item < nitems; item += gridDim.x) {
        int qt = item & 7;
        int rest = item >> 3;
        int h = rest % H, b = rest / H;
        if (qlim && qt * 64 >= qlim[b]) continue;
        int q0 = qt * 64 + wave * 16;
        size_t bh = (size_t)b * H + h;
        short8 aq = *(const short8*)&qb[(bh * S_ + q0 + c) * DH_ + quad * 8];
        const short* kbase = kb + bh * S_ * DH_;
        const short* vbase = vtb + bh * DH_ * S_;
        int limit = limit_arr[b];
        int nchunks = (limit + 127) >> 7;
        float lrow[4] = {0.f, 0.f, 0.f, 0.f};
        f32x4 o0 = zero, o1 = zero;
        for (int kc = 0; kc < nchunks; ++kc) {
            f32x4 s[8];
#pragma unroll
            for (int nt = 0; nt < 8; ++nt) {
                short8 bk = *(const short8*)&kbase[(size_t)(kc * 128 + nt * 16 + c) * DH_ + quad * 8];
                s[nt] = __builtin_amdgcn_mfma_f32_16x16x32_bf16(aq, bk, zero, 0, 0, 0);
            }
#pragma unroll
            for (int nt = 0; nt < 8; ++nt) {
                bool ok = (kc * 128 + nt * 16 + c) < limit;
#pragma unroll
                for (int r = 0; r < 4; ++r) {
                    float p = ok ? exp2f(s[nt][r]) : 0.f;
                    s[nt][r] = p;
                    lrow[r] += p;
                }
            }
#pragma unroll
            for (int nt = 0; nt < 8; ++nt)
#pragma unroll
                for (int r = 0; r < 4; ++r)
                    Pt[quad * 4 + r][nt * 16 + c] = f2bf(s[nt][r]);
            // wave-private Pt: intra-wave ds ordering via lgkmcnt, no barrier
#pragma unroll
            for (int kk = 0; kk < 4; ++kk) {
                short8 ap = *(const short8*)&Pt[c][kk * 32 + quad * 8];
                short8 b0 = *(const short8*)&vbase[(size_t)c * S_ + kc * 128 + kk * 32 + quad * 8];
                short8 b1 = *(const short8*)&vbase[(size_t)(16 + c) * S_ + kc * 128 + kk * 32 + quad * 8];
                o0 = __builtin_amdgcn_mfma_f32_16x16x32_bf16(ap, b0, o0, 0, 0, 0);
                o1 = __builtin_amdgcn_mfma_f32_16x16x32_bf16(ap, b1, o1, 0, 0, 0);
            }
        }
#pragma unroll
        for (int r = 0; r < 4; ++r) {
            float l = lrow[r];
            l += __shfl_xor(l, 1);
            l += __shfl_xor(l, 2);
            l += __shfl_xor(l, 4);
            l += __shfl_xor(l, 8);
            float inv = 1.f / l;
            int row = quad * 4 + r;
            size_t base = (size_t)(b * S_ + q0 + row) * D + h * DH_;
            o[base + c] = f2bf(o0[r] * inv);
            o[base + 16 + c] = f2bf(o1[r] * inv);
        }
    }
}

// ---------------------------------------------------------------------------
// stage: residual + LayerNorm — one wave per row
// ---------------------------------------------------------------------------
template <int D>
__device__ __forceinline__ void ln_stage(const short* x, const short* h,
    const float* g, const float* be, short* out, const int* live) {
    constexpr int E = D / 64;
    int gw = blockIdx.x * 4 + (threadIdx.x >> 6), lane = threadIdx.x & 63;
    int nw = gridDim.x * 4;
    for (int row = gw; row < BS_; row += nw) {
        if (live && (row & (S_ - 1)) >= live[row >> 9]) continue;
        const short* px = x + (size_t)row * D + lane * E;
        const short* ph = h + (size_t)row * D + lane * E;
        float v[E];
        float s = 0.f;
#pragma unroll
        for (int e = 0; e < E; ++e) {
            v[e] = bf2f(px[e]) + bf2f(ph[e]);
            s += v[e];
        }
#pragma unroll
        for (int off = 32; off; off >>= 1) s += __shfl_xor(s, off, 64);
        float m = s / D;
        float s2 = 0.f;
#pragma unroll
        for (int e = 0; e < E; ++e) {
            float d = v[e] - m;
            s2 += d * d;
        }
#pragma unroll
        for (int off = 32; off; off >>= 1) s2 += __shfl_xor(s2, off, 64);
        float rstd = rsqrtf(s2 / D + 1e-5f);
        short* po = out + (size_t)row * D + lane * E;
#pragma unroll
        for (int e = 0; e < E; ++e)
            po[e] = f2bf((v[e] - m) * rstd * g[lane * E + e] + be[lane * E + e]);
    }
}

// ---------------------------------------------------------------------------
// stage: decoder embed — one wave per row (128 cols, 2/lane)
// ---------------------------------------------------------------------------
__device__ __forceinline__ void dec_embed_stage(const MegaArgs& a) {
    int gw = blockIdx.x * 4 + (threadIdx.x >> 6), lane = threadIdx.x & 63;
    int nw = gridDim.x * 4;
    for (int bs = gw; bs < BS_; bs += nw) {
        int b = bs >> 9;
        int vis = a.visible[bs];
        size_t srcrow = (size_t)(b * S_ + a.idx[bs]) * DD_;
#pragma unroll
        for (int j = 0; j < 2; ++j) {
            int d = j * 64 + lane;
            short val = vis ? a.bt[srcrow + d] : f2bf(a.mask_tok[d]);
            a.bx[(size_t)bs * DD_ + d] = val;
        }
    }
}

// ---------------------------------------------------------------------------
// stage: heads — one wave per row
// ---------------------------------------------------------------------------
__device__ __forceinline__ void head_stage(const MegaArgs& a) {
    int gw = blockIdx.x * 4 + (threadIdx.x >> 6), lane = threadIdx.x & 63;
    int nw = gridDim.x * 4;
    for (int row = gw; row < BS_; row += nw) {
        float v0 = bf2f(a.bx[(size_t)row * DD_ + lane]);
        float v1 = bf2f(a.bx[(size_t)row * DD_ + 64 + lane]);
        float q = v0 * a.qh_w[lane] + v1 * a.qh_w[64 + lane];
        float dt = v0 * a.dth_w[lane] + v1 * a.dth_w[64 + lane];
#pragma unroll
        for (int off = 32; off; off >>= 1) {
            q += __shfl_xor(q, off, 64);
            dt += __shfl_xor(dt, off, 64);
        }
        if (lane == 0) {
            a.out[(size_t)row * 2 + 0] = q + a.qh_b[0];
            a.out[(size_t)row * 2 + 1] = dt + a.dth_b[0];
        }
    }
}

// ---------------------------------------------------------------------------
// THE mega kernel: entire forward pass, grid.sync() between stages.
// No early returns anywhere (cooperative barrier discipline).
// ---------------------------------------------------------------------------
__global__ void __launch_bounds__(256, 2) mega_kernel(MegaArgs a) {
    cg::grid_group grid = cg::this_grid();
    __shared__ __align__(16) char smem[16896];

    // stage 0: plan (blocks <32) + weight conv (blocks >=32)
    if (blockIdx.x < B_) plan_stage(smem, a);
    else conv_stage(a);
    grid.sync();

    embed_stage(a);
    grid.sync();

    // -------------------- encoder --------------------
    for (int l = 0; l < LE_; ++l) {
        gemm_stage<false, true>(smem, a.bx, a.w_eqkv + (size_t)l * 3 * DE_ * DE_,
            a.eqkv_b + (size_t)l * 3 * DE_, nullptr, BS_, 3 * DE_, DE_,
            a.qbuf, a.kbuf, a.vtbuf, HE_, DE_, a.counts);
        grid.sync();
        attn_stage(smem, a.qbuf, a.kbuf, a.vtbuf, a.counts, a.counts, a.battn, HE_, DE_);
        grid.sync();
        gemm_stage<false, false>(smem, a.battn, a.w_eout + (size_t)l * DE_ * DE_,
            a.eout_b + (size_t)l * DE_, a.bt, BS_, DE_, DE_,
            nullptr, nullptr, nullptr, 0, 0, a.counts);
        grid.sync();
        ln_stage<DE_>(a.bx, a.bt, a.eg1 + (size_t)l * DE_, a.eb1 + (size_t)l * DE_, a.bx, a.counts);
        grid.sync();
        gemm_stage<true, false>(smem, a.bx, a.w_ef1 + (size_t)l * FE_ * DE_,
            a.ef1_b + (size_t)l * FE_, a.hid, BS_, FE_, DE_,
            nullptr, nullptr, nullptr, 0, 0, a.counts);
        grid.sync();
        gemm_stage<false, false>(smem, a.hid, a.w_ef2 + (size_t)l * DE_ * FE_,
            a.ef2_b + (size_t)l * DE_, a.bt, BS_, DE_, FE_,
            nullptr, nullptr, nullptr, 0, 0, a.counts);
        grid.sync();
        ln_stage<DE_>(a.bx, a.bt, a.eg2 + (size_t)l * DE_, a.eb2 + (size_t)l * DE_, a.bx, a.counts);
        grid.sync();
    }

    // -------------------- enc -> dec --------------------
    gemm_stage<false, false>(smem, a.bx, a.w_e2d, nullptr, a.bt, BS_, DD_, DE_,
        nullptr, nullptr, nullptr, 0, 0, a.counts);
    grid.sync();
    dec_embed_stage(a);
    grid.sync();

    // -------------------- decoder --------------------
    for (int l = 0; l < LD_; ++l) {
        gemm_stage<false, true>(smem, a.bx, a.w_dqkv + (size_t)l * 3 * DD_ * DD_,
            a.dqkv_b + (size_t)l * 3 * DD_, nullptr, BS_, 3 * DD_, DD_,
            a.qbuf, a.kbuf, a.vtbuf, HD_, DD_, nullptr);
        grid.sync();
        attn_stage(smem, a.qbuf, a.kbuf, a.vtbuf, a.lengths, nullptr, a.battn, HD_, DD_);
        grid.sync();
        gemm_stage<false, false>(smem, a.battn, a.w_dout + (size_t)l * DD_ * DD_,
            a.dout_b + (size_t)l * DD_, a.bt, BS_, DD_, DD_,
            nullptr, nullptr, nullptr, 0, 0, nullptr);
        grid.sync();
        ln_stage<DD_>(a.bx, a.bt, a.dg1 + (size_t)l * DD_, a.db1 + (size_t)l * DD_, a.bx, nullptr);
        grid.sync();
        gemm_stage<true, false>(smem, a.bx, a.w_df1 + (size_t)l * FD_ * DD_,
            a.df1_b + (size_t)l * FD_, a.hid, BS_, FD_, DD_,
            nullptr, nullptr, nullptr, 0, 0, nullptr);
        grid.sync();
        gemm_stage<false, false>(smem, a.hid, a.w_df2 + (size_t)l * DD_ * FD_,
            a.df2_b + (size_t)l * DD_, a.bt, BS_, DD_, FD_,
            nullptr, nullptr, nullptr, 0, 0, nullptr);
        grid.sync();
        ln_stage<DD_>(a.bx, a.bt, a.dg2 + (size_t)l * DD_, a.db2 + (size_t)l * DD_, a.bx, nullptr);
        grid.sync();
    }

    head_stage(a);
}

// ---------------------------------------------------------------------------
extern "C" void kernel_launch(void* const* d_in, const int* in_sizes, int n_in,
                              void* d_out, int out_size, void* d_ws, size_t ws_size,
                              hipStream_t stream) {
    MegaArgs a;
    a.ev      = (const float*)d_in[0];
    a.am      = (const int*)d_in[1];
    a.pm      = (const int*)d_in[2];
    a.w_in    = (const float*)d_in[3];
    a.b_in    = (const float*)d_in[4];
    const float* eqkv_w = (const float*)d_in[5];
    a.eqkv_b  = (const float*)d_in[6];
    const float* eout_w = (const float*)d_in[7];
    a.eout_b  = (const float*)d_in[8];
    const float* ef1_w  = (const float*)d_in[9];
    a.ef1_b   = (const float*)d_in[10];
    const float* ef2_w  = (const float*)d_in[11];
    a.ef2_b   = (const float*)d_in[12];
    a.eg1     = (const float*)d_in[13];
    a.eb1     = (const float*)d_in[14];
    a.eg2     = (const float*)d_in[15];
    a.eb2     = (const float*)d_in[16];
    a.mask_tok= (const float*)d_in[17];
    const float* e2d_w  = (const float*)d_in[18];
    const float* dqkv_w = (const float*)d_in[19];
    a.dqkv_b  = (const float*)d_in[20];
    const float* dout_w = (const float*)d_in[21];
    a.dout_b  = (const float*)d_in[22];
    const float* df1_w  = (const float*)d_in[23];
    a.df1_b   = (const float*)d_in[24];
    const float* df2_w  = (const float*)d_in[25];
    a.df2_b   = (const float*)d_in[26];
    a.dg1     = (const float*)d_in[27];
    a.db1     = (const float*)d_in[28];
    a.dg2     = (const float*)d_in[29];
    a.db2     = (const float*)d_in[30];
    a.qh_w    = (const float*)d_in[31];
    a.qh_b    = (const float*)d_in[32];
    a.dth_w   = (const float*)d_in[33];
    a.dth_b   = (const float*)d_in[34];
    a.out     = (float*)d_out;

    char* ws = (char*)d_ws;
    a.counts  = (int*)ws;
    a.lengths = a.counts + 32;
    a.order   = a.lengths + 32;
    a.visible = a.order + BS_;
    a.idx     = a.visible + BS_;

    short* wb = (short*)(ws + 256 * 1024);
    a.w_eqkv = wb;
    a.w_eout = a.w_eqkv + L_EQKV;
    a.w_ef1  = a.w_eout + L_EOUT;
    a.w_ef2  = a.w_ef1 + L_EF1;
    a.w_e2d  = a.w_ef2 + L_EF2;
    a.w_dqkv = a.w_e2d + L_E2D;
    a.w_dout = a.w_dqkv + L_DQKV;
    a.w_df1  = a.w_dout + L_DOUT;
    a.w_df2  = a.w_df1 + L_DF1;

    a.bx    = (short*)(ws + 12 * 1024 * 1024);
    a.qbuf  = a.bx   + (size_t)BS_ * DE_;
    a.kbuf  = a.qbuf + (size_t)B_ * HE_ * S_ * DH_;
    a.vtbuf = a.kbuf + (size_t)B_ * HE_ * S_ * DH_;
    a.battn = a.vtbuf + (size_t)B_ * HE_ * S_ * DH_;
    a.bt    = a.battn + (size_t)BS_ * DE_;
    a.hid   = a.bt + (size_t)BS_ * DE_;

    a.csrc[0] = eqkv_w; a.cdst[0] = a.w_eqkv; a.clen[0] = L_EQKV;
    a.csrc[1] = eout_w; a.cdst[1] = a.w_eout; a.clen[1] = L_EOUT;
    a.csrc[2] = ef1_w;  a.cdst[2] = a.w_ef1;  a.clen[2] = L_EF1;
    a.csrc[3] = ef2_w;  a.cdst[3] = a.w_ef2;  a.clen[3] = L_EF2;
    a.csrc[4] = e2d_w;  a.cdst[4] = a.w_e2d;  a.clen[4] = L_E2D;
    a.csrc[5] = dqkv_w; a.cdst[5] = a.w_dqkv; a.clen[5] = L_DQKV;
    a.csrc[6] = dout_w; a.cdst[6] = a.w_dout; a.clen[6] = L_DOUT;
    a.csrc[7] = df1_w;  a.cdst[7] = a.w_df1;  a.clen[7] = L_DF1;
    a.csrc[8] = df2_w;  a.cdst[8] = a.w_df2;  a.clen[8] = L_DF2;

    // grid size: 2 blocks/CU if the kernel's occupancy allows, else 1
    int maxb = 0;
    (void)hipOccupancyMaxActiveBlocksPerMultiprocessor(&maxb, mega_kernel, 256, 0);
    int nb = (maxb >= 2) ? 512 : 256;

    void* kargs[] = { &a };
    (void)hipLaunchCooperativeKernel((const void*)mega_kernel, dim3(nb), dim3(256),
                                     kargs, 0, stream);
}

// Round 12
// 877.342 us; speedup vs baseline: 3.7376x; 3.7376x over previous
//
#include <hip/hip_runtime.h>
#include <hip/hip_bf16.h>

#define B_ 32
#define S_ 512
#define IN_ 19
#define DE_ 256
#define DD_ 128
#define HE_ 8
#define HD_ 4
#define LE_ 6
#define LD_ 2
#define FE_ 1024
#define FD_ 512
#define DH_ 32

typedef __attribute__((ext_vector_type(8))) short short8;
typedef __attribute__((ext_vector_type(4))) float f32x4;

__device__ __forceinline__ short f2bf(float f) {
    union { float f; unsigned u; } x; x.f = f;
    unsigned r = x.u + 0x7fff + ((x.u >> 16) & 1);
    return (short)(r >> 16);
}
__device__ __forceinline__ float bf2f(short s) {
    union { unsigned u; float f; } x; x.u = ((unsigned)(unsigned short)s) << 16;
    return x.f;
}

#define GLL16(g, l) __builtin_amdgcn_global_load_lds( \
    (const __attribute__((address_space(1))) void*)(g), \
    (__attribute__((address_space(3))) void*)(l), 16, 0, 0)

// (1/sqrt(32)) * log2(e), folded into Q at the QKV epilogue
#define QSCALE 0.2550653169f

// ---------------------------------------------------------------------------
// weight fp32 -> bf16 conversion
// ---------------------------------------------------------------------------
#define NCONV 9
struct ConvTab {
    const float* src[NCONV];
    short* dst[NCONV];
    int len[NCONV];
};
__global__ __launch_bounds__(256) void conv_kernel(ConvTab tab, int total) {
    int i = blockIdx.x * 256 + threadIdx.x;
    if (i >= total) return;
    int j = i;
    for (int e = 0; e < NCONV; ++e) {
        if (j < tab.len[e]) { tab.dst[e][j] = f2bf(tab.src[e][j]); return; }
        j -= tab.len[e];
    }
}

// ---------------------------------------------------------------------------
// plan: packed dual scan (visible-count + am-length), one 512-thr block/batch
// ---------------------------------------------------------------------------
__global__ __launch_bounds__(S_) void plan_kernel(
    const int* __restrict__ am, const int* __restrict__ pm,
    int* __restrict__ counts, int* __restrict__ lengths, int* __restrict__ order,
    int* __restrict__ visible, int* __restrict__ idx) {
    int b = blockIdx.x, s = threadIdx.x;
    __shared__ int sc[S_];
    int a = (am[b * S_ + s] != 0);
    int v = a && (pm[b * S_ + s] == 0);
    visible[b * S_ + s] = v;
    sc[s] = v | (a << 16);
    __syncthreads();
#pragma unroll
    for (int off = 1; off < S_; off <<= 1) {
        int t = (s >= off) ? sc[s - off] : 0;
        __syncthreads();
        sc[s] += t;
        __syncthreads();
    }
    int incl = sc[s] & 0xffff;
    int tot = sc[S_ - 1];
    int total = tot & 0xffff;
    if (s == 0) { counts[b] = total; lengths[b] = tot >> 16; }
    idx[b * S_ + s] = (incl > 0) ? incl - 1 : 0;
    if (v) order[b * S_ + incl - 1] = s;
    else   order[b * S_ + total + (s - incl)] = s;
}

// ---------------------------------------------------------------------------
// encoder embed
// ---------------------------------------------------------------------------
__global__ __launch_bounds__(DE_) void enc_embed_kernel(
    const float* __restrict__ ev, const float* __restrict__ w, const float* __restrict__ bias,
    const int* __restrict__ counts, const int* __restrict__ order, short* __restrict__ out) {
    int bs = blockIdx.x;
    int b = bs / S_, s = bs % S_;
    int d = threadIdx.x;
    __shared__ float e[IN_];
    bool padded = (s >= counts[b]);
    int src = order[bs];
    if (threadIdx.x < IN_)
        e[threadIdx.x] = padded ? 0.f : ev[(size_t)(b * S_ + src) * IN_ + threadIdx.x];
    __syncthreads();
    float acc = bias[d];
#pragma unroll
    for (int i = 0; i < IN_; ++i) acc += e[i] * w[d * IN_ + i];
    out[(size_t)bs * DE_ + d] = padded ? f2bf(0.f) : f2bf(acc);
}

// ---------------------------------------------------------------------------
// MFMA bf16 GEMM, 64x64 tile, BK=32, global_load_lds(16B).
// 4x the block count of the 128-tile version: gives TLP (>=2 blocks/CU on
// decoder + enc qkv/f1 stages) to overlap the per-k-step staging latency
// that is fully exposed at <1 block/CU. live: dead-encoder-tile skip.
// ---------------------------------------------------------------------------
template <bool RELU, bool QKV>
__global__ __launch_bounds__(256) void gemm_mfma(
    const short* __restrict__ A, const short* __restrict__ Wt, const float* __restrict__ bias,
    short* __restrict__ C, int M, int N, int K,
    short* __restrict__ qb, short* __restrict__ kb, short* __restrict__ vtb, int H, int D,
    const int* __restrict__ live) {
    int bm = blockIdx.y * 64, bn = blockIdx.x * 64;
    if (live && (bm & (S_ - 1)) >= live[bm >> 9]) return;   // dead encoder tile
    __shared__ short As[64][32];
    __shared__ short Bs[64][32];
    int t = threadIdx.x;
    int wave = t >> 6, lane = t & 63;
    int wm = (wave >> 1) * 32, wn = (wave & 1) * 32;
    int c = lane & 15, quad = lane >> 4;
    f32x4 acc[2][2];
#pragma unroll
    for (int i = 0; i < 2; ++i)
#pragma unroll
        for (int j = 0; j < 2; ++j) acc[i][j] = (f32x4){0.f, 0.f, 0.f, 0.f};

    // wave stages 16 rows of A and 16 rows of B per k-step (1 KiB per GLL16)
    const short* gA = A + (size_t)(bm + wave * 16 + (lane >> 2)) * K + (lane & 3) * 8;
    const short* gB = Wt + (size_t)(bn + wave * 16 + (lane >> 2)) * K + (lane & 3) * 8;

    for (int k0 = 0; k0 < K; k0 += 32) {
        GLL16(gA + k0, &As[wave * 16][0]);
        GLL16(gB + k0, &Bs[wave * 16][0]);
        __syncthreads();
        short8 a0 = *(const short8*)&As[wm + c][quad * 8];
        short8 a1 = *(const short8*)&As[wm + 16 + c][quad * 8];
        short8 b0 = *(const short8*)&Bs[wn + c][quad * 8];
        short8 b1 = *(const short8*)&Bs[wn + 16 + c][quad * 8];
        acc[0][0] = __builtin_amdgcn_mfma_f32_16x16x32_bf16(a0, b0, acc[0][0], 0, 0, 0);
        acc[0][1] = __builtin_amdgcn_mfma_f32_16x16x32_bf16(a0, b1, acc[0][1], 0, 0, 0);
        acc[1][0] = __builtin_amdgcn_mfma_f32_16x16x32_bf16(a1, b0, acc[1][0], 0, 0, 0);
        acc[1][1] = __builtin_amdgcn_mfma_f32_16x16x32_bf16(a1, b1, acc[1][1], 0, 0, 0);
        __syncthreads();
    }
#pragma unroll
    for (int mt = 0; mt < 2; ++mt)
#pragma unroll
        for (int nt = 0; nt < 2; ++nt)
#pragma unroll
            for (int r = 0; r < 4; ++r) {
                int R = bm + wm + mt * 16 + quad * 4 + r;
                int Ncol = bn + wn + nt * 16 + c;
                float v = acc[mt][nt][r] + (bias ? bias[Ncol] : 0.f);
                if (RELU) v = fmaxf(v, 0.f);
                if (!QKV) {
                    C[(size_t)R * N + Ncol] = f2bf(v);
                } else {
                    int s = R & (S_ - 1), b2 = R >> 9;
                    if (Ncol < D) {
                        int h = Ncol >> 5, d = Ncol & 31;
                        qb[(((size_t)b2 * H + h) * S_ + s) * DH_ + d] = f2bf(v * QSCALE);
                    } else if (Ncol < 2 * D) {
                        int n2 = Ncol - D, h = n2 >> 5, d = n2 & 31;
                        kb[(((size_t)b2 * H + h) * S_ + s) * DH_ + d] = f2bf(v);
                    } else {
                        int n2 = Ncol - 2 * D, h = n2 >> 5, d = n2 & 31;
                        vtb[(((size_t)b2 * H + h) * DH_ + d) * S_ + s] = f2bf(v);
                    }
                }
            }
}

// ---------------------------------------------------------------------------
// Flash MFMA attention, prefix-mask chunk skipping; optional q-tile skipping.
// ---------------------------------------------------------------------------
__global__ __launch_bounds__(256) void attn_flash(
    const short* __restrict__ qb, const short* __restrict__ kb, const short* __restrict__ vtb,
    const int* __restrict__ limit_arr, const int* __restrict__ qlim,
    short* __restrict__ o, int H, int D) {
    int b = blockIdx.z, h = blockIdx.y;
    if (qlim && (int)(blockIdx.x * 64) >= qlim[b]) return;
    int wave = threadIdx.x >> 6, lane = threadIdx.x & 63;
    int q0 = blockIdx.x * 64 + wave * 16;
    int c = lane & 15, quad = lane >> 4;
    size_t bh = (size_t)b * H + h;
    __shared__ short PtAll[4][16][132];
    short (*Pt)[132] = PtAll[wave];

    f32x4 zero = (f32x4){0.f, 0.f, 0.f, 0.f};
    short8 aq = *(const short8*)&qb[(bh * S_ + q0 + c) * DH_ + quad * 8];
    const short* kbase = kb + bh * S_ * DH_;
    const short* vbase = vtb + bh * DH_ * S_;

    int limit = limit_arr[b];
    int nchunks = (limit + 127) >> 7;

    float lrow[4] = {0.f, 0.f, 0.f, 0.f};
    f32x4 o0 = zero, o1 = zero;

    for (int kc = 0; kc < nchunks; ++kc) {
        f32x4 s[8];
#pragma unroll
        for (int nt = 0; nt < 8; ++nt) {
            short8 bk = *(const short8*)&kbase[(size_t)(kc * 128 + nt * 16 + c) * DH_ + quad * 8];
            s[nt] = __builtin_amdgcn_mfma_f32_16x16x32_bf16(aq, bk, zero, 0, 0, 0);
        }
#pragma unroll
        for (int nt = 0; nt < 8; ++nt) {
            bool ok = (kc * 128 + nt * 16 + c) < limit;
#pragma unroll
            for (int r = 0; r < 4; ++r) {
                float p = ok ? exp2f(s[nt][r]) : 0.f;
                s[nt][r] = p;
                lrow[r] += p;
            }
        }
#pragma unroll
        for (int nt = 0; nt < 8; ++nt)
#pragma unroll
            for (int r = 0; r < 4; ++r)
                Pt[quad * 4 + r][nt * 16 + c] = f2bf(s[nt][r]);
        // no barrier: Pt is wave-private, intra-wave ds ordering via lgkmcnt
#pragma unroll
        for (int kk = 0; kk < 4; ++kk) {
            short8 ap = *(const short8*)&Pt[c][kk * 32 + quad * 8];
            short8 b0 = *(const short8*)&vbase[(size_t)c * S_ + kc * 128 + kk * 32 + quad * 8];
            short8 b1 = *(const short8*)&vbase[(size_t)(16 + c) * S_ + kc * 128 + kk * 32 + quad * 8];
            o0 = __builtin_amdgcn_mfma_f32_16x16x32_bf16(ap, b0, o0, 0, 0, 0);
            o1 = __builtin_amdgcn_mfma_f32_16x16x32_bf16(ap, b1, o1, 0, 0, 0);
        }
    }
#pragma unroll
    for (int r = 0; r < 4; ++r) {
        float l = lrow[r];
        l += __shfl_xor(l, 1);
        l += __shfl_xor(l, 2);
        l += __shfl_xor(l, 4);
        l += __shfl_xor(l, 8);
        float inv = 1.f / l;
        int row = quad * 4 + r;
        size_t base = (size_t)(b * S_ + q0 + row) * D + h * DH_;
        o[base + c] = f2bf(o0[r] * inv);
        o[base + 16 + c] = f2bf(o1[r] * inv);
    }
}

// ---------------------------------------------------------------------------
// out = LN(x + h) * g + b — one WAVE per row; optional dead-row skip
// ---------------------------------------------------------------------------
template <int D>
__global__ __launch_bounds__(64) void add_ln_kernel(
    const short* __restrict__ x, const short* __restrict__ h,
    const float* __restrict__ g, const float* __restrict__ be,
    short* __restrict__ out, const int* __restrict__ live) {
    constexpr int E = D / 64;
    int row = blockIdx.x, t = threadIdx.x;
    if (live && (row & (S_ - 1)) >= live[row >> 9]) return;
    const short* px = x + (size_t)row * D + t * E;
    const short* ph = h + (size_t)row * D + t * E;
    float v[E];
    float s = 0.f;
#pragma unroll
    for (int e = 0; e < E; ++e) {
        v[e] = bf2f(px[e]) + bf2f(ph[e]);
        s += v[e];
    }
#pragma unroll
    for (int off = 32; off; off >>= 1) s += __shfl_xor(s, off, 64);
    float m = s / D;
    float s2 = 0.f;
#pragma unroll
    for (int e = 0; e < E; ++e) {
        float d = v[e] - m;
        s2 += d * d;
    }
#pragma unroll
    for (int off = 32; off; off >>= 1) s2 += __shfl_xor(s2, off, 64);
    float rstd = rsqrtf(s2 / D + 1e-5f);
    short* po = out + (size_t)row * D + t * E;
#pragma unroll
    for (int e = 0; e < E; ++e)
        po[e] = f2bf((v[e] - m) * rstd * g[t * E + e] + be[t * E + e]);
}

// ---------------------------------------------------------------------------
// decoder embed
// ---------------------------------------------------------------------------
__global__ __launch_bounds__(DD_) void dec_embed_kernel(
    const short* __restrict__ dec_vis, const float* __restrict__ mask_token,
    const int* __restrict__ visible, const int* __restrict__ idx, short* __restrict__ out) {
    int bs = blockIdx.x, d = threadIdx.x;
    int b = bs / S_;
    short val = visible[bs] ? dec_vis[(size_t)(b * S_ + idx[bs]) * DD_ + d]
                            : f2bf(mask_token[d]);
    out[(size_t)bs * DD_ + d] = val;
}

// ---------------------------------------------------------------------------
// heads (fp32 out)
// ---------------------------------------------------------------------------
__global__ __launch_bounds__(64) void head_kernel(
    const short* __restrict__ x, const float* __restrict__ qw, const float* __restrict__ qb,
    const float* __restrict__ dw, const float* __restrict__ db, float* __restrict__ out) {
    int row = blockIdx.x, t = threadIdx.x;
    float v0 = bf2f(x[(size_t)row * DD_ + t]);
    float v1 = bf2f(x[(size_t)row * DD_ + 64 + t]);
    float q = v0 * qw[t] + v1 * qw[64 + t];
    float dt = v0 * dw[t] + v1 * dw[64 + t];
#pragma unroll
    for (int off = 32; off; off >>= 1) {
        q += __shfl_xor(q, off, 64);
        dt += __shfl_xor(dt, off, 64);
    }
    if (t == 0) {
        out[(size_t)row * 2 + 0] = q + qb[0];
        out[(size_t)row * 2 + 1] = dt + db[0];
    }
}

// ---------------------------------------------------------------------------
extern "C" void kernel_launch(void* const* d_in, const int* in_sizes, int n_in,
                              void* d_out, int out_size, void* d_ws, size_t ws_size,
                              hipStream_t stream) {
    const float* ev      = (const float*)d_in[0];
    const int*  am       = (const int*)d_in[1];
    const int*  pm       = (const int*)d_in[2];
    const float* w_in    = (const float*)d_in[3];
    const float* b_in    = (const float*)d_in[4];
    const float* eqkv_w  = (const float*)d_in[5];
    const float* eqkv_b  = (const float*)d_in[6];
    const float* eout_w  = (const float*)d_in[7];
    const float* eout_b  = (const float*)d_in[8];
    const float* ef1_w   = (const float*)d_in[9];
    const float* ef1_b   = (const float*)d_in[10];
    const float* ef2_w   = (const float*)d_in[11];
    const float* ef2_b   = (const float*)d_in[12];
    const float* eg1     = (const float*)d_in[13];
    const float* eb1     = (const float*)d_in[14];
    const float* eg2     = (const float*)d_in[15];
    const float* eb2     = (const float*)d_in[16];
    const float* mask_tok= (const float*)d_in[17];
    const float* e2d_w   = (const float*)d_in[18];
    const float* dqkv_w  = (const float*)d_in[19];
    const float* dqkv_b  = (const float*)d_in[20];
    const float* dout_w  = (const float*)d_in[21];
    const float* dout_b  = (const float*)d_in[22];
    const float* df1_w   = (const float*)d_in[23];
    const float* df1_b   = (const float*)d_in[24];
    const float* df2_w   = (const float*)d_in[25];
    const float* df2_b   = (const float*)d_in[26];
    const float* dg1     = (const float*)d_in[27];
    const float* db1     = (const float*)d_in[28];
    const float* dg2     = (const float*)d_in[29];
    const float* db2     = (const float*)d_in[30];
    const float* qh_w    = (const float*)d_in[31];
    const float* qh_b    = (const float*)d_in[32];
    const float* dth_w   = (const float*)d_in[33];
    const float* dth_b   = (const float*)d_in[34];
    float* out = (float*)d_out;

    const int BS = B_ * S_;
    char* ws = (char*)d_ws;
    int* counts  = (int*)ws;
    int* lengths = counts + 32;
    int* order   = lengths + 32;
    int* visible = order + BS;
    int* idx     = visible + BS;

    short* wb = (short*)(ws + 256 * 1024);
    const int L_eqkv = LE_ * 3 * DE_ * DE_;
    const int L_eout = LE_ * DE_ * DE_;
    const int L_ef1  = LE_ * FE_ * DE_;
    const int L_ef2  = LE_ * DE_ * FE_;
    const int L_e2d  = DD_ * DE_;
    const int L_dqkv = LD_ * 3 * DD_ * DD_;
    const int L_dout = LD_ * DD_ * DD_;
    const int L_df1  = LD_ * FD_ * DD_;
    const int L_df2  = LD_ * DD_ * FD_;
    short* w_eqkv = wb;
    short* w_eout = w_eqkv + L_eqkv;
    short* w_ef1  = w_eout + L_eout;
    short* w_ef2  = w_ef1 + L_ef1;
    short* w_e2d  = w_ef2 + L_ef2;
    short* w_dqkv = w_e2d + L_e2d;
    short* w_dout = w_dqkv + L_dqkv;
    short* w_df1  = w_dout + L_dout;
    short* w_df2  = w_df1 + L_df1;
    const int convTotal = L_eqkv + L_eout + L_ef1 + L_ef2 + L_e2d + L_dqkv + L_dout + L_df1 + L_df2;

    short* bx    = (short*)(ws + 12 * 1024 * 1024);
    short* qbuf  = bx   + (size_t)BS * DE_;
    short* kbuf  = qbuf + (size_t)B_ * HE_ * S_ * DH_;
    short* vtbuf = kbuf + (size_t)B_ * HE_ * S_ * DH_;
    short* battn = vtbuf + (size_t)B_ * HE_ * S_ * DH_;
    short* bt    = battn + (size_t)BS * DE_;
    short* hid   = bt + (size_t)BS * DE_;

    ConvTab tab;
    tab.src[0] = eqkv_w; tab.dst[0] = w_eqkv; tab.len[0] = L_eqkv;
    tab.src[1] = eout_w; tab.dst[1] = w_eout; tab.len[1] = L_eout;
    tab.src[2] = ef1_w;  tab.dst[2] = w_ef1;  tab.len[2] = L_ef1;
    tab.src[3] = ef2_w;  tab.dst[3] = w_ef2;  tab.len[3] = L_ef2;
    tab.src[4] = e2d_w;  tab.dst[4] = w_e2d;  tab.len[4] = L_e2d;
    tab.src[5] = dqkv_w; tab.dst[5] = w_dqkv; tab.len[5] = L_dqkv;
    tab.src[6] = dout_w; tab.dst[6] = w_dout; tab.len[6] = L_dout;
    tab.src[7] = df1_w;  tab.dst[7] = w_df1;  tab.len[7] = L_df1;
    tab.src[8] = df2_w;  tab.dst[8] = w_df2;  tab.len[8] = L_df2;
    conv_kernel<<<(convTotal + 255) / 256, 256, 0, stream>>>(tab, convTotal);

    plan_kernel<<<B_, S_, 0, stream>>>(am, pm, counts, lengths, order, visible, idx);
    enc_embed_kernel<<<BS, DE_, 0, stream>>>(ev, w_in, b_in, counts, order, bx);

    // -------------------- encoder (dead tiles skipped via counts) ----------
    for (int l = 0; l < LE_; ++l) {
        gemm_mfma<false, true><<<dim3(3 * DE_ / 64, BS / 64), 256, 0, stream>>>(
            bx, w_eqkv + (size_t)l * 3 * DE_ * DE_, eqkv_b + (size_t)l * 3 * DE_,
            nullptr, BS, 3 * DE_, DE_, qbuf, kbuf, vtbuf, HE_, DE_, counts);
        attn_flash<<<dim3(S_ / 64, HE_, B_), 256, 0, stream>>>(
            qbuf, kbuf, vtbuf, counts, counts, battn, HE_, DE_);
        gemm_mfma<false, false><<<dim3(DE_ / 64, BS / 64), 256, 0, stream>>>(
            battn, w_eout + (size_t)l * DE_ * DE_, eout_b + (size_t)l * DE_,
            bt, BS, DE_, DE_, nullptr, nullptr, nullptr, 0, 0, counts);
        add_ln_kernel<DE_><<<BS, 64, 0, stream>>>(
            bx, bt, eg1 + (size_t)l * DE_, eb1 + (size_t)l * DE_, bx, counts);
        gemm_mfma<true, false><<<dim3(FE_ / 64, BS / 64), 256, 0, stream>>>(
            bx, w_ef1 + (size_t)l * FE_ * DE_, ef1_b + (size_t)l * FE_,
            hid, BS, FE_, DE_, nullptr, nullptr, nullptr, 0, 0, counts);
        gemm_mfma<false, false><<<dim3(DE_ / 64, BS / 64), 256, 0, stream>>>(
            hid, w_ef2 + (size_t)l * DE_ * FE_, ef2_b + (size_t)l * DE_,
            bt, BS, DE_, FE_, nullptr, nullptr, nullptr, 0, 0, counts);
        add_ln_kernel<DE_><<<BS, 64, 0, stream>>>(
            bx, bt, eg2 + (size_t)l * DE_, eb2 + (size_t)l * DE_, bx, counts);
    }

    // -------------------- enc -> dec --------------------
    gemm_mfma<false, false><<<dim3(DD_ / 64, BS / 64), 256, 0, stream>>>(
        bx, w_e2d, nullptr, bt, BS, DD_, DE_, nullptr, nullptr, nullptr, 0, 0, counts);
    dec_embed_kernel<<<BS, DD_, 0, stream>>>(bt, mask_tok, visible, idx, bx);

    // -------------------- decoder (all rows live) --------------------
    for (int l = 0; l < LD_; ++l) {
        gemm_mfma<false, true><<<dim3(3 * DD_ / 64, BS / 64), 256, 0, stream>>>(
            bx, w_dqkv + (size_t)l * 3 * DD_ * DD_, dqkv_b + (size_t)l * 3 * DD_, nullptr,
            BS, 3 * DD_, DD_, qbuf, kbuf, vtbuf, HD_, DD_, nullptr);
        attn_flash<<<dim3(S_ / 64, HD_, B_), 256, 0, stream>>>(
            qbuf, kbuf, vtbuf, lengths, nullptr, battn, HD_, DD_);
        gemm_mfma<false, false><<<dim3(DD_ / 64, BS / 64), 256, 0, stream>>>(
            battn, w_dout + (size_t)l * DD_ * DD_, dout_b + (size_t)l * DD_,
            bt, BS, DD_, DD_, nullptr, nullptr, nullptr, 0, 0, nullptr);
        add_ln_kernel<DD_><<<BS, 64, 0, stream>>>(
            bx, bt, dg1 + (size_t)l * DD_, db1 + (size_t)l * DD_, bx, nullptr);
        gemm_mfma<true, false><<<dim3(FD_ / 64, BS / 64), 256, 0, stream>>>(
            bx, w_df1 + (size_t)l * FD_ * DD_, df1_b + (size_t)l * FD_,
            hid, BS, FD_, DD_, nullptr, nullptr, nullptr, 0, 0, nullptr);
        gemm_mfma<false, false><<<dim3(DD_ / 64, BS / 64), 256, 0, stream>>>(
            hid, w_df2 + (size_t)l * DD_ * FD_, df2_b + (size_t)l * DD_,
            bt, BS, DD_, FD_, nullptr, nullptr, nullptr, 0, 0, nullptr);
        add_ln_kernel<DD_><<<BS, 64, 0, stream>>>(
            bx, bt, dg2 + (size_t)l * DD_, db2 + (size_t)l * DD_, bx, nullptr);
    }

    head_kernel<<<BS, 64, 0, stream>>>(bx, qh_w, qh_b, dth_w, dth_b, out);
}